// Round 14
// baseline (105.802 us; speedup 1.0000x reference)
//
#include <hip/hip_runtime.h>

#define NS 65536
#define DD 32
#define RR 128
#define SPB 16            // samples per block
#define STR 132           // padded LDS row stride (floats)
#define NBLK (NS / SPB)   // 4096 blocks

typedef float f2 __attribute__((ext_vector_type(2)));

static __device__ __forceinline__ f2 pkfma(f2 a, f2 b, f2 c) {
    f2 d;
    asm("v_pk_fma_f32 %0, %1, %2, %3" : "=v"(d) : "v"(a), "v"(b), "v"(c));
    return d;
}

// neighbor-lane (xor 1) value via DPP quad_perm [1,0,3,2] — VALU pipe only.
static __device__ __forceinline__ float dpp_x1(float x) {
    return __int_as_float(__builtin_amdgcn_update_dpp(
        0, __float_as_int(x), 0xB1 /*quad_perm(1,0,3,2)*/, 0xF, 0xF, true));
}

// R18 = R16 (half-split, best @ ~40us kernel) + dual-pipe x feed.
// Pipe arithmetic after R17 killed the prologue theory: per tile the PER-CU
// LDS pipe serves 4 waves x (64 bcast ds_read_b128 + 16 ds_write) + ~30
// per-lane epilogue b128s ~= 1.3-1.8Kcy, vs ~700cy VALU per SIMD -> LDS pipe
// is the largest identified component (~18-22us of the 40us kernel). Every
// kernel since R7 fed 100% of x through it. R12 tested split-feed but at
// 2 waves/SIMD (latency uncovered -> confounded regression). R14 fixed
// residency; retry in the correct regime: per thread, float4s g=0,1 from LDS
// and g=2,3 from global X via L1 (staging leaves the row L1-hot; parity-
// divergent addresses force VMEM; wave touches one 128B line). LDS read
// instrs/tile halve; VMEM half rides an idle pipe; latency covered by
// one-DOSAMPLE prefetch distance x 4 waves/SIMD.
// Same values, same op order => bit-identical outputs (absmax 8.077936e-28).
// (256,4): budget 128 >> ~102 demand (anti-R8 margin); R16 showed 5th wave
// buys nothing.
__global__ __launch_bounds__(256, 4) void anfis_main(
    const float* __restrict__ X, const float* __restrict__ A,
    const float* __restrict__ B, const float* __restrict__ C,
    float* __restrict__ out_pred, float* __restrict__ out_str,
    float* __restrict__ out_norm)
{
    __shared__ float SBUF[SPB * STR];   // strengths, row = sample-in-block
    __shared__ float PBUF[SPB * STR];   // strength * rule_out
    __shared__ float XT[SPB * DD];      // block's X tile (2KB)
    __shared__ float pS[SPB][8];
    __shared__ float pD[SPB][8];
    __shared__ float scale_lds[SPB];

    const int tid   = threadIdx.x;
    const int rule  = tid >> 1;         // 0..127
    const int half  = tid & 1;          // dim-half: 0 -> dims 0-15, 1 -> 16-31
    const int xoff  = half * 16;
    const int nbase = blockIdx.x * SPB;

    // ---- stage X tile to LDS (2KB, 1 float4 for first 128 threads).
    //      Side effect: tile is L1-resident for the VMEM feed half. ----
    if (tid < 128)
        ((float4*)XT)[tid] = ((const float4*)(X + (size_t)nbase * DD))[tid];

    // per-lane global base for this thread's dim-half (parity-divergent
    // address -> compiler must emit VMEM, not SMEM)
    const float* xg = X + (size_t)nbase * DD + xoff;

    // ---- per-thread HALF-rule params -> VGPR pairs (48 + 1 regs) ----
    f2 w01_[4], w23_[4], n01_[4], n23_[4], c01_[4], c23_[4];
    float biasv;
    {
        const float4* av = (const float4*)(A + rule * DD + xoff);
        const float4* bv = (const float4*)(B + rule * DD + xoff);
        const float*  cp = C + rule * (DD + 1) + xoff;
        #pragma unroll
        for (int i = 0; i < 4; ++i) {
            float4 va = av[i], vb = bv[i];
            float w0 = 0.8493218003f * __builtin_amdgcn_rcpf(fmaxf(vb.x, 1e-8f));
            float w1 = 0.8493218003f * __builtin_amdgcn_rcpf(fmaxf(vb.y, 1e-8f));
            float w2 = 0.8493218003f * __builtin_amdgcn_rcpf(fmaxf(vb.z, 1e-8f));
            float w3 = 0.8493218003f * __builtin_amdgcn_rcpf(fmaxf(vb.w, 1e-8f));
            w01_[i] = f2{w0, w1};            w23_[i] = f2{w2, w3};
            n01_[i] = f2{-va.x * w0, -va.y * w1};
            n23_[i] = f2{-va.z * w2, -va.w * w3};
            c01_[i] = f2{cp[4*i + 0], cp[4*i + 1]};
            c23_[i] = f2{cp[4*i + 2], cp[4*i + 3]};
        }
        biasv = half ? C[rule * (DD + 1) + DD] : 0.0f;  // bias lives in half 1
    }
    __syncthreads();                    // XT visible to all 4 waves

    // Pin params: forbid rematerialization/reload inside the sample loop.
    #pragma unroll
    for (int i = 0; i < 4; ++i)
        asm("" : "+v"(w01_[i]), "+v"(w23_[i]), "+v"(n01_[i]),
                 "+v"(n23_[i]), "+v"(c01_[i]), "+v"(c23_[i]));
    asm("" : "+v"(biasv));

    // parity-selected output row buffer: even lanes write strengths,
    // odd lanes write strength*rule_out — one non-divergent ds_write each.
    float* wbuf = half ? PBUF : SBUF;

    // dual-pipe load of this thread's 16 dims of sample jj:
    //   g=0,1 from LDS (2 ds_read_b128, 2-addr broadcast, conflict-free)
    //   g=2,3 from global/L1 (2 VMEM dwordx4 within one L1-hot 128B line)
    #define LOADQ(buf, jj) { \
        buf[0] = *(const float4*)&XT[(jj) * DD + xoff + 0]; \
        buf[1] = *(const float4*)&XT[(jj) * DD + xoff + 4]; \
        buf[2] = *(const float4*)(xg + (jj) * DD + 8); \
        buf[3] = *(const float4*)(xg + (jj) * DD + 12); }

    // one sample: 12 pk_fma + 2 dpp-reduces + exp2 + 1 LDS write
    #define DOSAMPLE(buf, jj) { \
        f2 s01 = f2{0.f, 0.f}, s23 = f2{0.f, 0.f}; \
        f2 r01 = f2{biasv, 0.f}, r23 = f2{0.f, 0.f}; \
        _Pragma("unroll") \
        for (int g = 0; g < 4; ++g) { \
            const f2* xp2 = (const f2*)&buf[g]; \
            f2 x01 = xp2[0], x23 = xp2[1]; \
            f2 t01 = pkfma(x01, w01_[g], n01_[g]); \
            s01 = pkfma(t01, t01, s01); \
            r01 = pkfma(x01, c01_[g], r01); \
            f2 t23 = pkfma(x23, w23_[g], n23_[g]); \
            s23 = pkfma(t23, t23, s23); \
            r23 = pkfma(x23, c23_[g], r23); \
        } \
        float sh = (s01.x + s01.y) + (s23.x + s23.y); \
        float rh = (r01.x + r01.y) + (r23.x + r23.y); \
        float stot = sh + dpp_x1(sh); \
        float rtot = rh + dpp_x1(rh); \
        float st = __builtin_amdgcn_exp2f(-stot); \
        wbuf[(jj) * STR + rule] = half ? st * rtot : st; }

    float4 qa[4], qb[4];
    LOADQ(qa, 0)
    for (int j = 0; j < SPB; j += 2) {
        LOADQ(qb, j + 1)                    // prefetch j+1 while computing j
        DOSAMPLE(qa, j)
        if (j + 2 < SPB) LOADQ(qa, j + 2)   // prefetch j+2 while computing j+1
        DOSAMPLE(qb, j + 1)
    }
    #undef LOADQ
    #undef DOSAMPLE
    __syncthreads();

    // ---- per-sample sums over rules: 16 samples x 8 octants = 128 threads ----
    if (tid < 128) {
        int s = tid >> 3, o = tid & 7;      // 16B-group o covers 16 floats
        const float4* srow = (const float4*)&SBUF[s * STR + o * 16];
        const float4* prow = (const float4*)&PBUF[s * STR + o * 16];
        float ss = 0.f, dd = 0.f;
        #pragma unroll
        for (int k = 0; k < 4; ++k) {
            float4 v = srow[k]; ss += (v.x + v.y) + (v.z + v.w);
            float4 p = prow[k]; dd += (p.x + p.y) + (p.z + p.w);
        }
        pS[s][o] = ss; pD[s][o] = dd;
    }
    __syncthreads();
    float predv = 0.f;
    if (tid < SPB) {
        float ss = 0.f, dd = 0.f;
        #pragma unroll
        for (int o = 0; o < 8; ++o) { ss += pS[tid][o]; dd += pD[tid][o]; }
        float sc = 1.0f / (ss + 1e-8f);
        predv = dd * sc;                // store deferred past the barrier
        scale_lds[tid] = sc;
    }
    __syncthreads();
    if (tid < SPB) out_pred[nbase + tid] = predv;

    // ---- flush strengths + normalized, float4-coalesced (16x32 float4) ----
    #pragma unroll
    for (int it = 0; it < 2; ++it) {
        int f   = it * 256 + tid;       // float4 index over 16x32 tile
        int row = f >> 5;
        int col = f & 31;
        float4 v = *(const float4*)&SBUF[row * STR + col * 4];
        float sc = scale_lds[row];
        size_t base = ((size_t)(nbase + row)) * RR + col * 4;
        *(float4*)(out_str  + base) = v;
        *(float4*)(out_norm + base) = make_float4(v.x * sc, v.y * sc, v.z * sc, v.w * sc);
    }
}

extern "C" void kernel_launch(void* const* d_in, const int* in_sizes, int n_in,
                              void* d_out, int out_size, void* d_ws, size_t ws_size,
                              hipStream_t stream) {
    const float* X = (const float*)d_in[0];
    const float* A = (const float*)d_in[1];
    const float* B = (const float*)d_in[2];
    const float* C = (const float*)d_in[3];

    float* pred = (float*)d_out;
    float* str  = pred + NS;
    float* nrm  = str + (size_t)NS * RR;

    anfis_main<<<dim3(NBLK), dim3(256), 0, stream>>>(X, A, B, C, pred, str, nrm);
}

// Round 15
// 102.037 us; speedup vs baseline: 1.0369x; 1.0369x over previous
//
#include <hip/hip_runtime.h>

#define NS 65536
#define DD 32
#define RR 128
#define SPB 16            // samples per block
#define STR 132           // padded LDS row stride (floats)
#define NBLK (NS / SPB)   // 4096 blocks

typedef float f2 __attribute__((ext_vector_type(2)));

static __device__ __forceinline__ f2 pkfma(f2 a, f2 b, f2 c) {
    f2 d;
    asm("v_pk_fma_f32 %0, %1, %2, %3" : "=v"(d) : "v"(a), "v"(b), "v"(c));
    return d;
}
static __device__ __forceinline__ f2 pkadd(f2 a, f2 b) {
    f2 d;
    asm("v_pk_add_f32 %0, %1, %2" : "=v"(d) : "v"(a), "v"(b));
    return d;
}
// neighbor-lane (xor 1) value via DPP quad_perm [1,0,3,2] — VALU pipe only.
static __device__ __forceinline__ float dpp_x1(float x) {
    return __int_as_float(__builtin_amdgcn_update_dpp(
        0, __float_as_int(x), 0xB1 /*quad_perm(1,0,3,2)*/, 0xF, 0xF, true));
}

// R19 = R16 (best: harness 100.06) with ONE change: lean packed tail.
// R18 refuted the feed-pipe theory in the covered regime (43.96us, -4 vs R16)
// but gave full PMC: VGPR=48, VALUBusy 42.8%, Occ 40.9% -> no resource cap;
// idle slots are waves co-stalled on LDS latency/barriers. The one stream
// component never slimmed is the per-sample serial tail (6 adds + 2 dpp +
// 2 adds + exp2 + sel-mul ~= 13 of ~26 main-loop instrs, and a dependent
// chain gating each sample's ds_write + barrier arrival).
// New tail packs (s,r) into one f2: pkadd(s01,s23), pkadd(r01,r23), pack,
// 2 dpp + 1 pkadd -> both lanes get {stot,rtot} in ~9 ops, chain ~4 stages
// shorter. Reduction order changes (pair-transposed sums) -> absmax ~1e-25
// (precedent: R15 passed at 1.03e-25).
__global__ __launch_bounds__(256, 5) void anfis_main(
    const float* __restrict__ X, const float* __restrict__ A,
    const float* __restrict__ B, const float* __restrict__ C,
    float* __restrict__ out_pred, float* __restrict__ out_str,
    float* __restrict__ out_norm)
{
    __shared__ float SBUF[SPB * STR];   // strengths, row = sample-in-block
    __shared__ float PBUF[SPB * STR];   // strength * rule_out
    __shared__ float XT[SPB * DD];      // block's X tile (2KB)
    __shared__ float pS[SPB][8];
    __shared__ float pD[SPB][8];
    __shared__ float scale_lds[SPB];

    const int tid   = threadIdx.x;
    const int rule  = tid >> 1;         // 0..127
    const int half  = tid & 1;          // dim-half: 0 -> dims 0-15, 1 -> 16-31
    const int xoff  = half * 16;
    const int nbase = blockIdx.x * SPB;

    // ---- stage X tile to LDS (2KB, 1 float4 for first 128 threads) ----
    if (tid < 128)
        ((float4*)XT)[tid] = ((const float4*)(X + (size_t)nbase * DD))[tid];

    // ---- per-thread HALF-rule params -> VGPR pairs (48 + 1 regs) ----
    f2 w01_[4], w23_[4], n01_[4], n23_[4], c01_[4], c23_[4];
    float biasv;
    {
        const float4* av = (const float4*)(A + rule * DD + xoff);
        const float4* bv = (const float4*)(B + rule * DD + xoff);
        const float*  cp = C + rule * (DD + 1) + xoff;
        #pragma unroll
        for (int i = 0; i < 4; ++i) {
            float4 va = av[i], vb = bv[i];
            float w0 = 0.8493218003f * __builtin_amdgcn_rcpf(fmaxf(vb.x, 1e-8f));
            float w1 = 0.8493218003f * __builtin_amdgcn_rcpf(fmaxf(vb.y, 1e-8f));
            float w2 = 0.8493218003f * __builtin_amdgcn_rcpf(fmaxf(vb.z, 1e-8f));
            float w3 = 0.8493218003f * __builtin_amdgcn_rcpf(fmaxf(vb.w, 1e-8f));
            w01_[i] = f2{w0, w1};            w23_[i] = f2{w2, w3};
            n01_[i] = f2{-va.x * w0, -va.y * w1};
            n23_[i] = f2{-va.z * w2, -va.w * w3};
            c01_[i] = f2{cp[4*i + 0], cp[4*i + 1]};
            c23_[i] = f2{cp[4*i + 2], cp[4*i + 3]};
        }
        biasv = half ? C[rule * (DD + 1) + DD] : 0.0f;  // bias lives in half 1
    }
    __syncthreads();                    // XT visible to all 4 waves

    // Pin params: forbid rematerialization/reload inside the sample loop.
    #pragma unroll
    for (int i = 0; i < 4; ++i)
        asm("" : "+v"(w01_[i]), "+v"(w23_[i]), "+v"(n01_[i]),
                 "+v"(n23_[i]), "+v"(c01_[i]), "+v"(c23_[i]));
    asm("" : "+v"(biasv));

    // parity-selected output row buffer: even lanes write strengths,
    // odd lanes write strength*rule_out — one non-divergent ds_write each.
    float* wbuf = half ? PBUF : SBUF;

    // 16 dims of sample jj for this half: 4 ds_read_b128, 2 distinct
    // addresses per wave (32-way same-address broadcast = conflict-free).
    #define LOADQ(buf, jj) { _Pragma("unroll") \
        for (int g = 0; g < 4; ++g) \
            buf[g] = *(const float4*)&XT[(jj) * DD + xoff + g * 4]; }

    // one sample: 12 pk_fma + lean packed tail (2 pkadd + 2 add + 2 dpp +
    // 1 pkadd + exp2 + sel-mul) + 1 ds_write
    #define DOSAMPLE(buf, jj) { \
        f2 s01 = f2{0.f, 0.f}, s23 = f2{0.f, 0.f}; \
        f2 r01 = f2{biasv, 0.f}, r23 = f2{0.f, 0.f}; \
        _Pragma("unroll") \
        for (int g = 0; g < 4; ++g) { \
            const f2* xp2 = (const f2*)&buf[g]; \
            f2 x01 = xp2[0], x23 = xp2[1]; \
            f2 t01 = pkfma(x01, w01_[g], n01_[g]); \
            s01 = pkfma(t01, t01, s01); \
            r01 = pkfma(x01, c01_[g], r01); \
            f2 t23 = pkfma(x23, w23_[g], n23_[g]); \
            s23 = pkfma(t23, t23, s23); \
            r23 = pkfma(x23, c23_[g], r23); \
        } \
        f2 sv = pkadd(s01, s23); \
        f2 rv = pkadd(r01, r23); \
        f2 v  = f2{sv.x + sv.y, rv.x + rv.y};       /* {s_half, r_half} */ \
        f2 d  = f2{dpp_x1(v.x), dpp_x1(v.y)}; \
        v = pkadd(v, d);                            /* {stot, rtot} both lanes */ \
        float st = __builtin_amdgcn_exp2f(-v.x); \
        wbuf[(jj) * STR + rule] = half ? st * v.y : st; }

    float4 qa[4], qb[4];
    LOADQ(qa, 0)
    for (int j = 0; j < SPB; j += 2) {
        LOADQ(qb, j + 1)                    // prefetch j+1 while computing j
        DOSAMPLE(qa, j)
        if (j + 2 < SPB) LOADQ(qa, j + 2)   // prefetch j+2 while computing j+1
        DOSAMPLE(qb, j + 1)
    }
    #undef LOADQ
    #undef DOSAMPLE
    __syncthreads();

    // ---- per-sample sums over rules: 16 samples x 8 octants = 128 threads ----
    if (tid < 128) {
        int s = tid >> 3, o = tid & 7;      // 16B-group o covers 16 floats
        const float4* srow = (const float4*)&SBUF[s * STR + o * 16];
        const float4* prow = (const float4*)&PBUF[s * STR + o * 16];
        float ss = 0.f, dd = 0.f;
        #pragma unroll
        for (int k = 0; k < 4; ++k) {
            float4 v = srow[k]; ss += (v.x + v.y) + (v.z + v.w);
            float4 p = prow[k]; dd += (p.x + p.y) + (p.z + p.w);
        }
        pS[s][o] = ss; pD[s][o] = dd;
    }
    __syncthreads();
    float predv = 0.f;
    if (tid < SPB) {
        float ss = 0.f, dd = 0.f;
        #pragma unroll
        for (int o = 0; o < 8; ++o) { ss += pS[tid][o]; dd += pD[tid][o]; }
        float sc = 1.0f / (ss + 1e-8f);
        predv = dd * sc;                // store deferred past the barrier
        scale_lds[tid] = sc;
    }
    __syncthreads();
    if (tid < SPB) out_pred[nbase + tid] = predv;

    // ---- flush strengths + normalized, float4-coalesced (16x32 float4) ----
    #pragma unroll
    for (int it = 0; it < 2; ++it) {
        int f   = it * 256 + tid;       // float4 index over 16x32 tile
        int row = f >> 5;
        int col = f & 31;
        float4 v = *(const float4*)&SBUF[row * STR + col * 4];
        float sc = scale_lds[row];
        size_t base = ((size_t)(nbase + row)) * RR + col * 4;
        *(float4*)(out_str  + base) = v;
        *(float4*)(out_norm + base) = make_float4(v.x * sc, v.y * sc, v.z * sc, v.w * sc);
    }
}

extern "C" void kernel_launch(void* const* d_in, const int* in_sizes, int n_in,
                              void* d_out, int out_size, void* d_ws, size_t ws_size,
                              hipStream_t stream) {
    const float* X = (const float*)d_in[0];
    const float* A = (const float*)d_in[1];
    const float* B = (const float*)d_in[2];
    const float* C = (const float*)d_in[3];

    float* pred = (float*)d_out;
    float* str  = pred + NS;
    float* nrm  = str + (size_t)NS * RR;

    anfis_main<<<dim3(NBLK), dim3(256), 0, stream>>>(X, A, B, C, pred, str, nrm);
}

// Round 16
// 100.114 us; speedup vs baseline: 1.0568x; 1.0192x over previous
//
#include <hip/hip_runtime.h>

#define NS 65536
#define DD 32
#define RR 128
#define SPB 16            // samples per block
#define STR 132           // padded LDS row stride (floats)
#define NBLK (NS / SPB)   // 4096 blocks

typedef float f2 __attribute__((ext_vector_type(2)));

static __device__ __forceinline__ f2 pkfma(f2 a, f2 b, f2 c) {
    f2 d;
    asm("v_pk_fma_f32 %0, %1, %2, %3" : "=v"(d) : "v"(a), "v"(b), "v"(c));
    return d;
}
// neighbor-lane (xor 1) value via DPP quad_perm [1,0,3,2] — VALU pipe only.
static __device__ __forceinline__ float dpp_x1(float x) {
    return __int_as_float(__builtin_amdgcn_update_dpp(
        0, __float_as_int(x), 0xB1 /*quad_perm(1,0,3,2)*/, 0xF, 0xF, true));
}
// lane^2 via DPP quad_perm [2,3,0,1] — VALU pipe only.
static __device__ __forceinline__ float dpp_x2(float x) {
    return __int_as_float(__builtin_amdgcn_update_dpp(
        0, __float_as_int(x), 0x4E /*quad_perm(2,3,0,1)*/, 0xF, 0xF, true));
}
// lane^4 via ds_swizzle (xor_mask=4, and_mask=0x1F -> offset 0x101F).
static __device__ __forceinline__ float swz_x4(float x) {
    return __int_as_float(__builtin_amdgcn_ds_swizzle(__float_as_int(x), 0x101F));
}

// R20 = R16 exactly (best: harness 100.06; R19's packed tail regressed and is
// reverted) with ONE change: cross-lane epilogue.
// R18's full PMC: no resource cap (VGPR 48, Occ 41%), VALU 42.8% -> the idle
// 57% is co-stall on LDS latency + barrier convoys. The octant sum has used an
// LDS round-trip since R4: pS/pD write -> barrier -> divergent 16-thread
// read-back. But the 8 octant partials of each sample live in 8 CONSECUTIVE
// lanes (tid = s*8+o, waves 0-1) -> butterfly them in-register: xor1/xor2 via
// DPP quad-perm (VALU), xor4 via one ds_swizzle. Barriers/tile 3 -> 2, the
// 16-lane serialized tail and pS/pD traffic disappear.
// Main loop + flush byte-identical to R16 => out_str bit-identical; pred/norm
// shift only by the octant-tree reorder (~1e-25; R15 precedent passed).
__global__ __launch_bounds__(256, 5) void anfis_main(
    const float* __restrict__ X, const float* __restrict__ A,
    const float* __restrict__ B, const float* __restrict__ C,
    float* __restrict__ out_pred, float* __restrict__ out_str,
    float* __restrict__ out_norm)
{
    __shared__ float SBUF[SPB * STR];   // strengths, row = sample-in-block
    __shared__ float PBUF[SPB * STR];   // strength * rule_out
    __shared__ float XT[SPB * DD];      // block's X tile (2KB)
    __shared__ float scale_lds[SPB];

    const int tid   = threadIdx.x;
    const int rule  = tid >> 1;         // 0..127
    const int half  = tid & 1;          // dim-half: 0 -> dims 0-15, 1 -> 16-31
    const int xoff  = half * 16;
    const int nbase = blockIdx.x * SPB;

    // ---- stage X tile to LDS (2KB, 1 float4 for first 128 threads) ----
    if (tid < 128)
        ((float4*)XT)[tid] = ((const float4*)(X + (size_t)nbase * DD))[tid];

    // ---- per-thread HALF-rule params -> VGPR pairs (48 + 1 regs) ----
    f2 w01_[4], w23_[4], n01_[4], n23_[4], c01_[4], c23_[4];
    float biasv;
    {
        const float4* av = (const float4*)(A + rule * DD + xoff);
        const float4* bv = (const float4*)(B + rule * DD + xoff);
        const float*  cp = C + rule * (DD + 1) + xoff;
        #pragma unroll
        for (int i = 0; i < 4; ++i) {
            float4 va = av[i], vb = bv[i];
            float w0 = 0.8493218003f * __builtin_amdgcn_rcpf(fmaxf(vb.x, 1e-8f));
            float w1 = 0.8493218003f * __builtin_amdgcn_rcpf(fmaxf(vb.y, 1e-8f));
            float w2 = 0.8493218003f * __builtin_amdgcn_rcpf(fmaxf(vb.z, 1e-8f));
            float w3 = 0.8493218003f * __builtin_amdgcn_rcpf(fmaxf(vb.w, 1e-8f));
            w01_[i] = f2{w0, w1};            w23_[i] = f2{w2, w3};
            n01_[i] = f2{-va.x * w0, -va.y * w1};
            n23_[i] = f2{-va.z * w2, -va.w * w3};
            c01_[i] = f2{cp[4*i + 0], cp[4*i + 1]};
            c23_[i] = f2{cp[4*i + 2], cp[4*i + 3]};
        }
        biasv = half ? C[rule * (DD + 1) + DD] : 0.0f;  // bias lives in half 1
    }
    __syncthreads();                    // XT visible to all 4 waves

    // Pin params: forbid rematerialization/reload inside the sample loop.
    #pragma unroll
    for (int i = 0; i < 4; ++i)
        asm("" : "+v"(w01_[i]), "+v"(w23_[i]), "+v"(n01_[i]),
                 "+v"(n23_[i]), "+v"(c01_[i]), "+v"(c23_[i]));
    asm("" : "+v"(biasv));

    // parity-selected output row buffer: even lanes write strengths,
    // odd lanes write strength*rule_out — one non-divergent ds_write each.
    float* wbuf = half ? PBUF : SBUF;

    // 16 dims of sample jj for this half: 4 ds_read_b128, 2 distinct
    // addresses per wave (32-way same-address broadcast = conflict-free).
    #define LOADQ(buf, jj) { _Pragma("unroll") \
        for (int g = 0; g < 4; ++g) \
            buf[g] = *(const float4*)&XT[(jj) * DD + xoff + g * 4]; }

    // one sample: 24 pk_fma + 2 dpp-reduces + exp2 + 1 LDS write (R16 tail)
    #define DOSAMPLE(buf, jj) { \
        f2 s01 = f2{0.f, 0.f}, s23 = f2{0.f, 0.f}; \
        f2 r01 = f2{biasv, 0.f}, r23 = f2{0.f, 0.f}; \
        _Pragma("unroll") \
        for (int g = 0; g < 4; ++g) { \
            const f2* xp2 = (const f2*)&buf[g]; \
            f2 x01 = xp2[0], x23 = xp2[1]; \
            f2 t01 = pkfma(x01, w01_[g], n01_[g]); \
            s01 = pkfma(t01, t01, s01); \
            r01 = pkfma(x01, c01_[g], r01); \
            f2 t23 = pkfma(x23, w23_[g], n23_[g]); \
            s23 = pkfma(t23, t23, s23); \
            r23 = pkfma(x23, c23_[g], r23); \
        } \
        float sh = (s01.x + s01.y) + (s23.x + s23.y); \
        float rh = (r01.x + r01.y) + (r23.x + r23.y); \
        float stot = sh + dpp_x1(sh); \
        float rtot = rh + dpp_x1(rh); \
        float st = __builtin_amdgcn_exp2f(-stot); \
        wbuf[(jj) * STR + rule] = half ? st * rtot : st; }

    float4 qa[4], qb[4];
    LOADQ(qa, 0)
    for (int j = 0; j < SPB; j += 2) {
        LOADQ(qb, j + 1)                    // prefetch j+1 while computing j
        DOSAMPLE(qa, j)
        if (j + 2 < SPB) LOADQ(qa, j + 2)   // prefetch j+2 while computing j+1
        DOSAMPLE(qb, j + 1)
    }
    #undef LOADQ
    #undef DOSAMPLE
    __syncthreads();

    // ---- per-sample sums over rules, cross-lane: 16 samples x 8 octants =
    //      128 threads; octants of sample s are lanes s*8..s*8+7 (waves 0-1).
    //      Butterfly xor1/xor2 (DPP, VALU) + xor4 (ds_swizzle) — no barrier,
    //      no pS/pD round-trip, no divergent 16-thread tail. ----
    float predv = 0.f;
    const int srow_i = tid >> 3, oct = tid & 7;
    if (tid < 128) {
        const float4* srow = (const float4*)&SBUF[srow_i * STR + oct * 16];
        const float4* prow = (const float4*)&PBUF[srow_i * STR + oct * 16];
        float ss = 0.f, dd = 0.f;
        #pragma unroll
        for (int k = 0; k < 4; ++k) {
            float4 v = srow[k]; ss += (v.x + v.y) + (v.z + v.w);
            float4 p = prow[k]; dd += (p.x + p.y) + (p.z + p.w);
        }
        ss += dpp_x1(ss);  dd += dpp_x1(dd);
        ss += dpp_x2(ss);  dd += dpp_x2(dd);
        ss += swz_x4(ss);  dd += swz_x4(dd);
        float sc = 1.0f / (ss + 1e-8f);
        predv = dd * sc;
        if (oct == 0) scale_lds[srow_i] = sc;
    }
    __syncthreads();
    if (tid < 128 && oct == 0) out_pred[nbase + srow_i] = predv;

    // ---- flush strengths + normalized, float4-coalesced (16x32 float4) ----
    #pragma unroll
    for (int it = 0; it < 2; ++it) {
        int f   = it * 256 + tid;       // float4 index over 16x32 tile
        int row = f >> 5;
        int col = f & 31;
        float4 v = *(const float4*)&SBUF[row * STR + col * 4];
        float sc = scale_lds[row];
        size_t base = ((size_t)(nbase + row)) * RR + col * 4;
        *(float4*)(out_str  + base) = v;
        *(float4*)(out_norm + base) = make_float4(v.x * sc, v.y * sc, v.z * sc, v.w * sc);
    }
}

extern "C" void kernel_launch(void* const* d_in, const int* in_sizes, int n_in,
                              void* d_out, int out_size, void* d_ws, size_t ws_size,
                              hipStream_t stream) {
    const float* X = (const float*)d_in[0];
    const float* A = (const float*)d_in[1];
    const float* B = (const float*)d_in[2];
    const float* C = (const float*)d_in[3];

    float* pred = (float*)d_out;
    float* str  = pred + NS;
    float* nrm  = str + (size_t)NS * RR;

    anfis_main<<<dim3(NBLK), dim3(256), 0, stream>>>(X, A, B, C, pred, str, nrm);
}